// Round 16
// baseline (133.372 us; speedup 1.0000x reference)
//
#include <hip/hip_runtime.h>

#define NV   100000
#define NE   20000
#define NNZP 600000
#define DIM  128
#define SE   80     // ints per edge row: slot0 = count, ids at slots 1..79
#define SV   32     // u16 per vertex row: slot0 = count, ids at slots 1..31

#define NB_E 79                       // edge bins: e >> 8
#define NB_V 98                       // vertex bins: v >> 10
#define CAP_E 8448
#define CAP_V 6912
#define BIN_BLOCKS ((NNZP / 8 + 255) / 256)   // 293, 8 pairs per thread
#define G_CVT1 256                    // X-cvt blocks in k_bin  (first 2/5)
#define G_CVT2 384                    // X-cvt blocks in k_bucket (last 3/5)
#define XSPLIT4 1280000               // float4 split point (NV*32 * 2/5)
#define EDGE_BLOCKS (NE * 16 / 256)   // 1250 (quarter-wave per edge)
#define VF2_BLOCKS 1024               // persistent blocks
#define VF2_TILES  (NV / 16)          // 6250

typedef __attribute__((ext_vector_type(8))) short short8;
typedef __attribute__((ext_vector_type(4))) float f32x4;

__device__ __forceinline__ unsigned short f2b(float f) {
    unsigned x = __float_as_uint(f);
    unsigned r = x + 0x7fffu + ((x >> 16) & 1u);   // RNE
    return (unsigned short)(r >> 16);
}
__device__ __forceinline__ float blo(unsigned u) { return __uint_as_float(u << 16); }
__device__ __forceinline__ float bhi(unsigned u) { return __uint_as_float(u & 0xffff0000u); }
__device__ __forceinline__ unsigned pk2(float a, float b) {
    return (unsigned)f2b(a) | ((unsigned)f2b(b) << 16);
}

// ---------------------------------------------------------------------------
// B1: {bin pairs into dense per-bin runs} + {X[0:2/5] -> bf16, W -> M bf16}.
// M[c][k] = (1-beta)*(k==c) + beta*W[c][k]  (identity folded into weights).
__global__ __launch_bounds__(256) void k_bin(const float4* __restrict__ X4,
                                             const float4* __restrict__ W4,
                                             const float* __restrict__ beta_p,
                                             const int4* __restrict__ vertex4,
                                             const int4* __restrict__ edges4,
                                             unsigned* __restrict__ gpos_e,
                                             unsigned* __restrict__ gpos_v,
                                             unsigned* __restrict__ ebin,
                                             unsigned* __restrict__ vbin,
                                             ushort4* __restrict__ Xb,
                                             ushort4* __restrict__ Mb) {
    const int b = blockIdx.x;
    if (b >= BIN_BLOCKS) {
        int i = (b - BIN_BLOCKS) * 256 + threadIdx.x;
        for (int g = i; g < XSPLIT4; g += G_CVT1 * 256) {
            float4 v = X4[g];
            ushort4 o; o.x = f2b(v.x); o.y = f2b(v.y); o.z = f2b(v.z); o.w = f2b(v.w);
            Xb[g] = o;
        }
        if (i < DIM * DIM / 4) {
            const float beta = *beta_p;
            const float omb  = 1.0f - beta;
            float4 v = W4[i];
            int c  = i >> 5;            // row (output col)
            int k0 = (i & 31) * 4;      // starting k
            ushort4 o;
            o.x = f2b(beta * v.x + ((k0 + 0) == c ? omb : 0.f));
            o.y = f2b(beta * v.y + ((k0 + 1) == c ? omb : 0.f));
            o.z = f2b(beta * v.z + ((k0 + 2) == c ? omb : 0.f));
            o.w = f2b(beta * v.w + ((k0 + 3) == c ? omb : 0.f));
            Mb[i] = o;
        }
        return;
    }

    __shared__ unsigned he[NB_E], hv[NB_V], be[NB_E], bv[NB_V];
    const int tid = threadIdx.x;
    if (tid < NB_E) he[tid] = 0;
    if (tid < NB_V) hv[tid] = 0;
    __syncthreads();

    const int t8 = b * 256 + tid;
    const bool ok = t8 < NNZP / 8;
    int vA[8], eA[8];
    unsigned loe[8], lov[8];
    if (ok) {
        int4 v0 = vertex4[t8 * 2], v1 = vertex4[t8 * 2 + 1];
        int4 e0 = edges4[t8 * 2],  e1 = edges4[t8 * 2 + 1];
        vA[0]=v0.x; vA[1]=v0.y; vA[2]=v0.z; vA[3]=v0.w;
        vA[4]=v1.x; vA[5]=v1.y; vA[6]=v1.z; vA[7]=v1.w;
        eA[0]=e0.x; eA[1]=e0.y; eA[2]=e0.z; eA[3]=e0.w;
        eA[4]=e1.x; eA[5]=e1.y; eA[6]=e1.z; eA[7]=e1.w;
#pragma unroll
        for (int k = 0; k < 8; ++k) {
            loe[k] = atomicAdd(&he[eA[k] >> 8], 1u);
            lov[k] = atomicAdd(&hv[vA[k] >> 10], 1u);
        }
    }
    __syncthreads();

    for (int i = tid; i < NB_E; i += 256) {
        int bin = (i + b) % NB_E;
        unsigned h = he[bin];
        be[bin] = h ? atomicAdd(&gpos_e[bin], h) : 0u;
    }
    for (int i = tid; i < NB_V; i += 256) {
        int bin = (i + b) % NB_V;
        unsigned h = hv[bin];
        bv[bin] = h ? atomicAdd(&gpos_v[bin], h) : 0u;
    }
    __syncthreads();

    if (ok) {
#pragma unroll
        for (int k = 0; k < 8; ++k) {
            unsigned e = (unsigned)eA[k], v = (unsigned)vA[k];
            unsigned binE = e >> 8, binV = v >> 10;
            unsigned pe = be[binE] + loe[k];
            if (pe < CAP_E) ebin[(size_t)binE * CAP_E + pe] = (v << 8) | (e & 255u);
            unsigned pv = bv[binV] + lov[k];
            if (pv < CAP_V) vbin[(size_t)binV * CAP_V + pv] = (e << 10) | (v & 1023u);
        }
    }
}

// B2: {one block per bin, slots from LDS counters, count at slot 0}
//     + {X[2/5:] -> bf16 on the otherwise-idle CUs}.
__global__ __launch_bounds__(256) void k_bucket(const unsigned* __restrict__ gpos_e,
                                                const unsigned* __restrict__ gpos_v,
                                                const unsigned* __restrict__ ebin,
                                                const unsigned* __restrict__ vbin,
                                                int* __restrict__ bkt_e,
                                                unsigned short* __restrict__ bkt_v,
                                                const float4* __restrict__ X4,
                                                ushort4* __restrict__ Xb) {
    const int tid = threadIdx.x;
    if (blockIdx.x >= NB_E + NB_V) {
        int i = (blockIdx.x - NB_E - NB_V) * 256 + tid;
        const int n4 = NV * 32;
        for (int g = XSPLIT4 + i; g < n4; g += G_CVT2 * 256) {
            float4 v = X4[g];
            ushort4 o; o.x = f2b(v.x); o.y = f2b(v.y); o.z = f2b(v.z); o.w = f2b(v.w);
            Xb[g] = o;
        }
        return;
    }

    __shared__ unsigned cl[1024];
    if (blockIdx.x < NB_E) {
        const int b = blockIdx.x;
        cl[tid] = 0;
        __syncthreads();
        unsigned n = gpos_e[b]; if (n > CAP_E) n = CAP_E;
        const unsigned* src = ebin + (size_t)b * CAP_E;
        for (unsigned i = tid; i < n; i += 256) {
            unsigned pk = src[i];
            unsigned el = pk & 255u;
            unsigned slot = atomicAdd(&cl[el], 1u);
            if (slot < SE - 1)
                bkt_e[(size_t)(((unsigned)b << 8) | el) * SE + 1 + slot] = (int)(pk >> 8);
        }
        __syncthreads();
        int e = (b << 8) | tid;
        if (e < NE) bkt_e[(size_t)e * SE] = (int)cl[tid];
    } else {
        const int b = blockIdx.x - NB_E;
        for (int i = tid; i < 1024; i += 256) cl[i] = 0;
        __syncthreads();
        unsigned n = gpos_v[b]; if (n > CAP_V) n = CAP_V;
        const unsigned* src = vbin + (size_t)b * CAP_V;
        for (unsigned i = tid; i < n; i += 256) {
            unsigned pk = src[i];
            unsigned vl = pk & 1023u;
            unsigned slot = atomicAdd(&cl[vl], 1u);
            unsigned v = ((unsigned)b << 10) | vl;
            if (slot < SV - 1)
                bkt_v[(size_t)v * SV + 1 + slot] = (unsigned short)(pk >> 10);
        }
        __syncthreads();
        for (int i = tid; i < 1024; i += 256) {
            int v = (b << 10) + i;
            if (v < NV) bkt_v[(size_t)v * SV] = (unsigned short)cl[i];
        }
    }
}

// K1: per-edge mean from bf16 Xb. Quarter-wave per edge (16 lanes, uint4/lane).
__global__ __launch_bounds__(256) void k_edge(const uint4* __restrict__ X4b,
                                              const int4* __restrict__ bkt4,
                                              uint4* __restrict__ Xeb4) {
    const int t  = blockIdx.x * 256 + threadIdx.x;
    const int e  = t >> 4;                 // grid exact: NE*16 == 1250*256
    const int hl = t & 15;
    const int4* bp = bkt4 + (size_t)e * (SE / 4);
    int4 q0 = bp[0], q1 = bp[1], q2 = bp[2], q3 = bp[3], q4 = bp[4], q5 = bp[5],
         q6 = bp[6], q7 = bp[7], q8 = bp[8], q9 = bp[9], q10 = bp[10];
    unsigned c = (unsigned)q0.x; if (c > SE - 1) c = SE - 1;

    float a0=0.f,a1=0.f,a2=0.f,a3=0.f,a4=0.f,a5=0.f,a6=0.f,a7=0.f;

#define EACC(g_, w_) { a0 += (w_) * blo((g_).x); a1 += (w_) * bhi((g_).x); \
                       a2 += (w_) * blo((g_).y); a3 += (w_) * bhi((g_).y); \
                       a4 += (w_) * blo((g_).z); a5 += (w_) * bhi((g_).z); \
                       a6 += (w_) * blo((g_).w); a7 += (w_) * bhi((g_).w); }
#define EG8(qa, qb, base_) { \
        int id_[8] = {(qa).x, (qa).y, (qa).z, (qa).w, (qb).x, (qb).y, (qb).z, (qb).w}; \
        float wk_[8]; uint4 g_[8]; \
        _Pragma("unroll") \
        for (int k_ = 0; k_ < 8; ++k_) { \
            bool act_ = ((base_) + k_) < c; \
            wk_[k_] = act_ ? 1.0f : 0.0f; \
            g_[k_] = X4b[(size_t)(act_ ? (unsigned)id_[k_] : 0u) * 16 + hl]; \
        } \
        _Pragma("unroll") \
        for (int k_ = 0; k_ < 8; ++k_) EACC(g_[k_], wk_[k_]); }

    {   // batch 0: 3 ids from q0
        int id[3] = {q0.y, q0.z, q0.w};
        float wk[3]; uint4 g[3];
#pragma unroll
        for (int k = 0; k < 3; ++k) {
            bool act = (unsigned)k < c;
            wk[k] = act ? 1.0f : 0.0f;
            g[k] = X4b[(size_t)(act ? (unsigned)id[k] : 0u) * 16 + hl];
        }
#pragma unroll
        for (int k = 0; k < 3; ++k) EACC(g[k], wk[k]);
    }
    if (c > 3)  EG8(q1, q2, 3u);
    if (c > 11) EG8(q3, q4, 11u);
    if (c > 19) EG8(q5, q6, 19u);
    if (c > 27) EG8(q7, q8, 27u);
    if (c > 35) EG8(q9, q10, 35u);
    for (unsigned j = 43; j < c; j += 8) {   // rare tail (~1%)
        int4 qa = bp[(j + 1) >> 2];
        int4 qb = bp[((j + 1) >> 2) + 1];
        EG8(qa, qb, j);
    }
#undef EG8
#undef EACC

    const float inv = c ? 1.0f / (float)c : 1.0f;
    uint4 o;
    o.x = pk2(a0 * inv, a1 * inv);
    o.y = pk2(a2 * inv, a3 * inv);
    o.z = pk2(a4 * inv, a5 * inv);
    o.w = pk2(a6 * inv, a7 * inv);
    Xeb4[(size_t)e * 16 + hl] = o;
}

// K2: persistent fused {per-vertex mean + alpha-blend} + MFMA (out = Xi @ M).
// 1024 blocks x ~6 tiles; M-fragments hoisted to regs; next-tile X0/bkt
// prefetch issued before the MFMA phase so its latency hides.
__global__ __launch_bounds__(256, 4) void k_vf2(const uint4* __restrict__ Xeb4,
                                                const uint4* __restrict__ bktq,
                                                const float4* __restrict__ X04,
                                                const float* __restrict__ alpha_p,
                                                const unsigned short* __restrict__ Mb,
                                                float* __restrict__ out) {
    __shared__ __align__(16) unsigned sXi[16][68];   // 16 rows x 272B

    const int tid  = threadIdx.x;
    const int wid  = tid >> 6;
    const int lane = tid & 63;
    const int q    = lane >> 4;
    const int hl   = lane & 15;
    const int vrow = wid * 4 + q;
    const int lr   = lane & 15;
    const int lg   = lane >> 4;

    const float alpha = *alpha_p;

    // hoist M fragments: wave wid always owns col-tiles {2*wid, 2*wid+1}
    short8 mf[2][4];
#pragma unroll
    for (int ctl = 0; ctl < 2; ++ctl) {
        const unsigned short* Wp = Mb + (size_t)((wid * 2 + ctl) * 16 + lr) * DIM + lg * 8;
#pragma unroll
        for (int kt = 0; kt < 4; ++kt)
            mf[ctl][kt] = *(const short8*)(Wp + kt * 32);
    }

    int tile = blockIdx.x;
    int v = tile * 16 + vrow;
    float4 x0a = X04[(size_t)v * 32 + hl * 2];
    float4 x0b = X04[(size_t)v * 32 + hl * 2 + 1];
    uint4 q0 = bktq[(size_t)v * 4];
    uint4 q1 = bktq[(size_t)v * 4 + 1];

#define VACC(g_, w_) { a[0] += (w_) * blo((g_).x); a[1] += (w_) * bhi((g_).x); \
                       a[2] += (w_) * blo((g_).y); a[3] += (w_) * bhi((g_).y); \
                       a[4] += (w_) * blo((g_).z); a[5] += (w_) * bhi((g_).z); \
                       a[6] += (w_) * blo((g_).w); a[7] += (w_) * bhi((g_).w); }

    while (true) {
        unsigned c = q0.x & 0xffffu; if (c > SV - 1) c = SV - 1;
        float a[8] = {0.f, 0.f, 0.f, 0.f, 0.f, 0.f, 0.f, 0.f};

        {   // round A: 7 ids from q0
            unsigned id[7] = { q0.x >> 16, q0.y & 0xffffu, q0.y >> 16,
                               q0.z & 0xffffu, q0.z >> 16, q0.w & 0xffffu, q0.w >> 16 };
            float wk[7]; uint4 g[7];
#pragma unroll
            for (int k = 0; k < 7; ++k) {
                bool act = (unsigned)k < c;
                wk[k] = act ? 1.0f : 0.0f;
                g[k] = Xeb4[(size_t)(act ? id[k] : 0u) * 16 + hl];
            }
#pragma unroll
            for (int k = 0; k < 7; ++k) VACC(g[k], wk[k]);
        }
        if (c > 7) {   // round B: ids 7..14 already in regs
            unsigned id[8] = { q1.x & 0xffffu, q1.x >> 16, q1.y & 0xffffu, q1.y >> 16,
                               q1.z & 0xffffu, q1.z >> 16, q1.w & 0xffffu, q1.w >> 16 };
            float wk[8]; uint4 g[8];
#pragma unroll
            for (int k = 0; k < 8; ++k) {
                bool act = (unsigned)(7 + k) < c;
                wk[k] = act ? 1.0f : 0.0f;
                g[k] = Xeb4[(size_t)(act ? id[k] : 0u) * 16 + hl];
            }
#pragma unroll
            for (int k = 0; k < 8; ++k) VACC(g[k], wk[k]);
        }
        if (c > 15) {  // ids 15..30 (P ~ 4e-4)
            uint4 q2 = bktq[(size_t)v * 4 + 2];
            uint4 q3 = bktq[(size_t)v * 4 + 3];
            unsigned id[16] = { q2.x & 0xffffu, q2.x >> 16, q2.y & 0xffffu, q2.y >> 16,
                                q2.z & 0xffffu, q2.z >> 16, q2.w & 0xffffu, q2.w >> 16,
                                q3.x & 0xffffu, q3.x >> 16, q3.y & 0xffffu, q3.y >> 16,
                                q3.z & 0xffffu, q3.z >> 16, q3.w & 0xffffu, q3.w >> 16 };
            float wk[16]; uint4 g[16];
#pragma unroll
            for (int k = 0; k < 16; ++k) {
                bool act = (unsigned)(15 + k) < c;
                wk[k] = act ? 1.0f : 0.0f;
                g[k] = Xeb4[(size_t)(act ? id[k] : 0u) * 16 + hl];
            }
#pragma unroll
            for (int k = 0; k < 16; ++k) VACC(g[k], wk[k]);
        }

        const float s = (1.0f - alpha) * (c ? 1.0f / (float)c : 1.0f);
        uint4 xiw;
        xiw.x = pk2(s * a[0] + alpha * x0a.x, s * a[1] + alpha * x0a.y);
        xiw.y = pk2(s * a[2] + alpha * x0a.z, s * a[3] + alpha * x0a.w);
        xiw.z = pk2(s * a[4] + alpha * x0b.x, s * a[5] + alpha * x0b.y);
        xiw.w = pk2(s * a[6] + alpha * x0b.z, s * a[7] + alpha * x0b.w);
        *(uint4*)&sXi[vrow][hl * 4] = xiw;

        // prefetch next tile's chain heads (hides under barrier+MFMA+store)
        const int ntile = tile + VF2_BLOCKS;
        const bool more = ntile < VF2_TILES;
        const int nv = ntile * 16 + vrow;
        float4 nx0a, nx0b; uint4 nq0, nq1;
        if (more) {
            nx0a = X04[(size_t)nv * 32 + hl * 2];
            nx0b = X04[(size_t)nv * 32 + hl * 2 + 1];
            nq0 = bktq[(size_t)nv * 4];
            nq1 = bktq[(size_t)nv * 4 + 1];
        }
        __syncthreads();

        // MFMA epilogue: out = Xi @ M
        const char* ab = (const char*)&sXi[lr][0] + lg * 16;
        short8 af[4];
#pragma unroll
        for (int kt = 0; kt < 4; ++kt) af[kt] = *(const short8*)(ab + kt * 64);

#pragma unroll
        for (int ctl = 0; ctl < 2; ++ctl) {
            const int ct = wid * 2 + ctl;
            f32x4 acc = {};
#pragma unroll
            for (int kt = 0; kt < 4; ++kt)
                acc = __builtin_amdgcn_mfma_f32_16x16x32_bf16(af[kt], mf[ctl][kt], acc, 0, 0, 0);
#pragma unroll
            for (int rg = 0; rg < 4; ++rg) {
                int row = lg * 4 + rg;              // D: col=lane&15, row=lg*4+reg
                out[(size_t)(tile * 16 + row) * DIM + ct * 16 + lr] = acc[rg];
            }
        }
        __syncthreads();

        if (!more) break;
        tile = ntile; v = nv;
        x0a = nx0a; x0b = nx0b; q0 = nq0; q1 = nq1;
    }
#undef VACC
}

// ---------------------------------------------------------------------------
extern "C" void kernel_launch(void* const* d_in, const int* in_sizes, int n_in,
                              void* d_out, int out_size, void* d_ws, size_t ws_size,
                              hipStream_t stream) {
    const float* X      = (const float*)d_in[0];
    const int*   vertex = (const int*)  d_in[1];
    const int*   edges  = (const int*)  d_in[2];
    const float* alpha  = (const float*)d_in[3];
    const float* beta   = (const float*)d_in[4];
    const float* X0     = (const float*)d_in[5];
    const float* W      = (const float*)d_in[6];
    float*       out    = (float*)d_out;

    // ws layout (all 16B-aligned)
    unsigned* gpos_e = (unsigned*)d_ws;                        // NB_E (zeroed)
    unsigned* gpos_v = gpos_e + NB_E;                          // NB_V (zeroed)
    unsigned* ebin   = (unsigned*)d_ws + 256;                  // NB_E*CAP_E
    unsigned* vbin   = ebin + (size_t)NB_E * CAP_E;            // NB_V*CAP_V
    int*      bkt_e  = (int*)(vbin + (size_t)NB_V * CAP_V);    // NE*SE
    unsigned short* bkt_v = (unsigned short*)(bkt_e + (size_t)NE * SE); // NV*SV
    unsigned short* Mb = bkt_v + (size_t)NV * SV;              // DIM*DIM
    unsigned* Xeb = (unsigned*)(Mb + DIM * DIM);               // NE*64

    // bf16 X lives in d_out (dead before k_vf2 overwrites out)
    unsigned* Xb = (unsigned*)d_out;                           // NV*64

    hipMemsetAsync(d_ws, 0, (size_t)(NB_E + NB_V) * sizeof(unsigned), stream);

    k_bin<<<BIN_BLOCKS + G_CVT1, 256, 0, stream>>>(
        (const float4*)X, (const float4*)W, beta,
        (const int4*)vertex, (const int4*)edges,
        gpos_e, gpos_v, ebin, vbin, (ushort4*)Xb, (ushort4*)Mb);
    k_bucket<<<NB_E + NB_V + G_CVT2, 256, 0, stream>>>(
        gpos_e, gpos_v, ebin, vbin, bkt_e, bkt_v,
        (const float4*)X, (ushort4*)Xb);
    k_edge<<<EDGE_BLOCKS, 256, 0, stream>>>((const uint4*)Xb,
                                            (const int4*)bkt_e,
                                            (uint4*)Xeb);
    k_vf2<<<VF2_BLOCKS, 256, 0, stream>>>((const uint4*)Xeb, (const uint4*)bkt_v,
                                          (const float4*)X0, alpha,
                                          (const unsigned short*)Mb, out);
}

// Round 17
// 116.016 us; speedup vs baseline: 1.1496x; 1.1496x over previous
//
#include <hip/hip_runtime.h>

#define NV   100000
#define NE   20000
#define NNZP 600000
#define DIM  128
#define SE   80     // ints per edge row: slot0 = count, ids at slots 1..79
#define SV   32     // u16 per vertex row: slot0 = count, ids at slots 1..31

#define NB_E 79                       // edge bins: e >> 8
#define NB_V 98                       // vertex bins: v >> 10
#define CAP_E 8448
#define CAP_V 6912
#define BIN_BLOCKS ((NNZP / 8 + 255) / 256)   // 293, 8 pairs per thread
#define G_CVT1 256                    // X-cvt blocks in k_bin  (first 2/5)
#define G_CVT2 384                    // X-cvt blocks in k_bucket (last 3/5)
#define XSPLIT4 1280000               // float4 split point (NV*32 * 2/5)
#define EDGE_BLOCKS (NE * 16 / 256)   // 1250 (quarter-wave per edge)
#define VF2_BLOCKS (NV / 32)          // 3125 two-tile blocks

typedef __attribute__((ext_vector_type(8))) short short8;
typedef __attribute__((ext_vector_type(4))) float f32x4;

__device__ __forceinline__ unsigned short f2b(float f) {
    unsigned x = __float_as_uint(f);
    unsigned r = x + 0x7fffu + ((x >> 16) & 1u);   // RNE
    return (unsigned short)(r >> 16);
}
__device__ __forceinline__ float blo(unsigned u) { return __uint_as_float(u << 16); }
__device__ __forceinline__ float bhi(unsigned u) { return __uint_as_float(u & 0xffff0000u); }
__device__ __forceinline__ unsigned pk2(float a, float b) {
    return (unsigned)f2b(a) | ((unsigned)f2b(b) << 16);
}

// ---------------------------------------------------------------------------
// B1: {bin pairs into dense per-bin runs} + {X[0:2/5] -> bf16, W -> M bf16}.
// M[c][k] = (1-beta)*(k==c) + beta*W[c][k]  (identity folded into weights).
__global__ __launch_bounds__(256) void k_bin(const float4* __restrict__ X4,
                                             const float4* __restrict__ W4,
                                             const float* __restrict__ beta_p,
                                             const int4* __restrict__ vertex4,
                                             const int4* __restrict__ edges4,
                                             unsigned* __restrict__ gpos_e,
                                             unsigned* __restrict__ gpos_v,
                                             unsigned* __restrict__ ebin,
                                             unsigned* __restrict__ vbin,
                                             ushort4* __restrict__ Xb,
                                             ushort4* __restrict__ Mb) {
    const int b = blockIdx.x;
    if (b >= BIN_BLOCKS) {
        int i = (b - BIN_BLOCKS) * 256 + threadIdx.x;
        for (int g = i; g < XSPLIT4; g += G_CVT1 * 256) {
            float4 v = X4[g];
            ushort4 o; o.x = f2b(v.x); o.y = f2b(v.y); o.z = f2b(v.z); o.w = f2b(v.w);
            Xb[g] = o;
        }
        if (i < DIM * DIM / 4) {
            const float beta = *beta_p;
            const float omb  = 1.0f - beta;
            float4 v = W4[i];
            int c  = i >> 5;            // row (output col)
            int k0 = (i & 31) * 4;      // starting k
            ushort4 o;
            o.x = f2b(beta * v.x + ((k0 + 0) == c ? omb : 0.f));
            o.y = f2b(beta * v.y + ((k0 + 1) == c ? omb : 0.f));
            o.z = f2b(beta * v.z + ((k0 + 2) == c ? omb : 0.f));
            o.w = f2b(beta * v.w + ((k0 + 3) == c ? omb : 0.f));
            Mb[i] = o;
        }
        return;
    }

    __shared__ unsigned he[NB_E], hv[NB_V], be[NB_E], bv[NB_V];
    const int tid = threadIdx.x;
    if (tid < NB_E) he[tid] = 0;
    if (tid < NB_V) hv[tid] = 0;
    __syncthreads();

    const int t8 = b * 256 + tid;
    const bool ok = t8 < NNZP / 8;
    int vA[8], eA[8];
    unsigned loe[8], lov[8];
    if (ok) {
        int4 v0 = vertex4[t8 * 2], v1 = vertex4[t8 * 2 + 1];
        int4 e0 = edges4[t8 * 2],  e1 = edges4[t8 * 2 + 1];
        vA[0]=v0.x; vA[1]=v0.y; vA[2]=v0.z; vA[3]=v0.w;
        vA[4]=v1.x; vA[5]=v1.y; vA[6]=v1.z; vA[7]=v1.w;
        eA[0]=e0.x; eA[1]=e0.y; eA[2]=e0.z; eA[3]=e0.w;
        eA[4]=e1.x; eA[5]=e1.y; eA[6]=e1.z; eA[7]=e1.w;
#pragma unroll
        for (int k = 0; k < 8; ++k) {
            loe[k] = atomicAdd(&he[eA[k] >> 8], 1u);
            lov[k] = atomicAdd(&hv[vA[k] >> 10], 1u);
        }
    }
    __syncthreads();

    for (int i = tid; i < NB_E; i += 256) {
        int bin = (i + b) % NB_E;
        unsigned h = he[bin];
        be[bin] = h ? atomicAdd(&gpos_e[bin], h) : 0u;
    }
    for (int i = tid; i < NB_V; i += 256) {
        int bin = (i + b) % NB_V;
        unsigned h = hv[bin];
        bv[bin] = h ? atomicAdd(&gpos_v[bin], h) : 0u;
    }
    __syncthreads();

    if (ok) {
#pragma unroll
        for (int k = 0; k < 8; ++k) {
            unsigned e = (unsigned)eA[k], v = (unsigned)vA[k];
            unsigned binE = e >> 8, binV = v >> 10;
            unsigned pe = be[binE] + loe[k];
            if (pe < CAP_E) ebin[(size_t)binE * CAP_E + pe] = (v << 8) | (e & 255u);
            unsigned pv = bv[binV] + lov[k];
            if (pv < CAP_V) vbin[(size_t)binV * CAP_V + pv] = (e << 10) | (v & 1023u);
        }
    }
}

// B2: {one block per bin, slots from LDS counters, count at slot 0}
//     + {X[2/5:] -> bf16 on the otherwise-idle CUs}.
__global__ __launch_bounds__(256) void k_bucket(const unsigned* __restrict__ gpos_e,
                                                const unsigned* __restrict__ gpos_v,
                                                const unsigned* __restrict__ ebin,
                                                const unsigned* __restrict__ vbin,
                                                int* __restrict__ bkt_e,
                                                unsigned short* __restrict__ bkt_v,
                                                const float4* __restrict__ X4,
                                                ushort4* __restrict__ Xb) {
    const int tid = threadIdx.x;
    if (blockIdx.x >= NB_E + NB_V) {
        int i = (blockIdx.x - NB_E - NB_V) * 256 + tid;
        const int n4 = NV * 32;
        for (int g = XSPLIT4 + i; g < n4; g += G_CVT2 * 256) {
            float4 v = X4[g];
            ushort4 o; o.x = f2b(v.x); o.y = f2b(v.y); o.z = f2b(v.z); o.w = f2b(v.w);
            Xb[g] = o;
        }
        return;
    }

    __shared__ unsigned cl[1024];
    if (blockIdx.x < NB_E) {
        const int b = blockIdx.x;
        cl[tid] = 0;
        __syncthreads();
        unsigned n = gpos_e[b]; if (n > CAP_E) n = CAP_E;
        const unsigned* src = ebin + (size_t)b * CAP_E;
        for (unsigned i = tid; i < n; i += 256) {
            unsigned pk = src[i];
            unsigned el = pk & 255u;
            unsigned slot = atomicAdd(&cl[el], 1u);
            if (slot < SE - 1)
                bkt_e[(size_t)(((unsigned)b << 8) | el) * SE + 1 + slot] = (int)(pk >> 8);
        }
        __syncthreads();
        int e = (b << 8) | tid;
        if (e < NE) bkt_e[(size_t)e * SE] = (int)cl[tid];
    } else {
        const int b = blockIdx.x - NB_E;
        for (int i = tid; i < 1024; i += 256) cl[i] = 0;
        __syncthreads();
        unsigned n = gpos_v[b]; if (n > CAP_V) n = CAP_V;
        const unsigned* src = vbin + (size_t)b * CAP_V;
        for (unsigned i = tid; i < n; i += 256) {
            unsigned pk = src[i];
            unsigned vl = pk & 1023u;
            unsigned slot = atomicAdd(&cl[vl], 1u);
            unsigned v = ((unsigned)b << 10) | vl;
            if (slot < SV - 1)
                bkt_v[(size_t)v * SV + 1 + slot] = (unsigned short)(pk >> 10);
        }
        __syncthreads();
        for (int i = tid; i < 1024; i += 256) {
            int v = (b << 10) + i;
            if (v < NV) bkt_v[(size_t)v * SV] = (unsigned short)cl[i];
        }
    }
}

// K1: per-edge mean from bf16 Xb. Quarter-wave per edge (16 lanes, uint4/lane).
__global__ __launch_bounds__(256) void k_edge(const uint4* __restrict__ X4b,
                                              const int4* __restrict__ bkt4,
                                              uint4* __restrict__ Xeb4) {
    const int t  = blockIdx.x * 256 + threadIdx.x;
    const int e  = t >> 4;                 // grid exact: NE*16 == 1250*256
    const int hl = t & 15;
    const int4* bp = bkt4 + (size_t)e * (SE / 4);
    int4 q0 = bp[0], q1 = bp[1], q2 = bp[2], q3 = bp[3], q4 = bp[4], q5 = bp[5],
         q6 = bp[6], q7 = bp[7], q8 = bp[8], q9 = bp[9], q10 = bp[10];
    unsigned c = (unsigned)q0.x; if (c > SE - 1) c = SE - 1;

    float a0=0.f,a1=0.f,a2=0.f,a3=0.f,a4=0.f,a5=0.f,a6=0.f,a7=0.f;

#define EACC(g_, w_) { a0 += (w_) * blo((g_).x); a1 += (w_) * bhi((g_).x); \
                       a2 += (w_) * blo((g_).y); a3 += (w_) * bhi((g_).y); \
                       a4 += (w_) * blo((g_).z); a5 += (w_) * bhi((g_).z); \
                       a6 += (w_) * blo((g_).w); a7 += (w_) * bhi((g_).w); }
#define EG8(qa, qb, base_) { \
        int id_[8] = {(qa).x, (qa).y, (qa).z, (qa).w, (qb).x, (qb).y, (qb).z, (qb).w}; \
        float wk_[8]; uint4 g_[8]; \
        _Pragma("unroll") \
        for (int k_ = 0; k_ < 8; ++k_) { \
            bool act_ = ((base_) + k_) < c; \
            wk_[k_] = act_ ? 1.0f : 0.0f; \
            g_[k_] = X4b[(size_t)(act_ ? (unsigned)id_[k_] : 0u) * 16 + hl]; \
        } \
        _Pragma("unroll") \
        for (int k_ = 0; k_ < 8; ++k_) EACC(g_[k_], wk_[k_]); }

    {   // batch 0: 3 ids from q0
        int id[3] = {q0.y, q0.z, q0.w};
        float wk[3]; uint4 g[3];
#pragma unroll
        for (int k = 0; k < 3; ++k) {
            bool act = (unsigned)k < c;
            wk[k] = act ? 1.0f : 0.0f;
            g[k] = X4b[(size_t)(act ? (unsigned)id[k] : 0u) * 16 + hl];
        }
#pragma unroll
        for (int k = 0; k < 3; ++k) EACC(g[k], wk[k]);
    }
    if (c > 3)  EG8(q1, q2, 3u);
    if (c > 11) EG8(q3, q4, 11u);
    if (c > 19) EG8(q5, q6, 19u);
    if (c > 27) EG8(q7, q8, 27u);
    if (c > 35) EG8(q9, q10, 35u);
    for (unsigned j = 43; j < c; j += 8) {   // rare tail (~1%)
        int4 qa = bp[(j + 1) >> 2];
        int4 qb = bp[((j + 1) >> 2) + 1];
        EG8(qa, qb, j);
    }
#undef EG8
#undef EACC

    const float inv = c ? 1.0f / (float)c : 1.0f;
    uint4 o;
    o.x = pk2(a0 * inv, a1 * inv);
    o.y = pk2(a2 * inv, a3 * inv);
    o.z = pk2(a4 * inv, a5 * inv);
    o.w = pk2(a6 * inv, a7 * inv);
    Xeb4[(size_t)e * 16 + hl] = o;
}

// K2: two-tile fused {per-vertex mean + alpha-blend} + MFMA (out = Xi @ M).
// 3125 blocks x 32 vertices. Both tiles' chain heads (bkt + X0) issued at
// kernel start -> 2 independent gather chains per thread; one barrier; M
// fragments loaded once and used for both tiles' MFMA.
__global__ __launch_bounds__(256) void k_vf2(const uint4* __restrict__ Xeb4,
                                             const uint4* __restrict__ bktq,
                                             const float4* __restrict__ X04,
                                             const float* __restrict__ alpha_p,
                                             const unsigned short* __restrict__ Mb,
                                             float* __restrict__ out) {
    __shared__ __align__(16) unsigned sXi[32][68];   // 32 rows x 272B

    const int tid  = threadIdx.x;
    const int wid  = tid >> 6;
    const int lane = tid & 63;
    const int q    = lane >> 4;
    const int hl   = lane & 15;
    const int vrow = wid * 4 + q;
    const int lr   = lane & 15;
    const int lg   = lane >> 4;

    const float alpha = *alpha_p;
    const int v0 = blockIdx.x * 32 + vrow;          // tile 0 vertex
    const int v1 = v0 + 16;                         // tile 1 vertex

    // --- issue both tiles' chain heads up front ---
    uint4 q0a = bktq[(size_t)v0 * 4];
    uint4 q1a = bktq[(size_t)v0 * 4 + 1];
    uint4 q0b = bktq[(size_t)v1 * 4];
    uint4 q1b = bktq[(size_t)v1 * 4 + 1];
    float4 x0a0 = X04[(size_t)v0 * 32 + hl * 2];
    float4 x0b0 = X04[(size_t)v0 * 32 + hl * 2 + 1];
    float4 x0a1 = X04[(size_t)v1 * 32 + hl * 2];
    float4 x0b1 = X04[(size_t)v1 * 32 + hl * 2 + 1];

    // M fragments: wave wid owns col-tiles {2*wid, 2*wid+1} (both row-tiles)
    short8 mf[2][4];
#pragma unroll
    for (int ctl = 0; ctl < 2; ++ctl) {
        const unsigned short* Wp = Mb + (size_t)((wid * 2 + ctl) * 16 + lr) * DIM + lg * 8;
#pragma unroll
        for (int kt = 0; kt < 4; ++kt)
            mf[ctl][kt] = *(const short8*)(Wp + kt * 32);
    }

#define VACC(g_, w_) { a[0] += (w_) * blo((g_).x); a[1] += (w_) * bhi((g_).x); \
                       a[2] += (w_) * blo((g_).y); a[3] += (w_) * bhi((g_).y); \
                       a[4] += (w_) * blo((g_).z); a[5] += (w_) * bhi((g_).z); \
                       a[6] += (w_) * blo((g_).w); a[7] += (w_) * bhi((g_).w); }
#define GATHER_TILE(q0_, q1_, vv_, x0a_, x0b_, row_) { \
        unsigned c = (q0_).x & 0xffffu; if (c > SV - 1) c = SV - 1; \
        float a[8] = {0.f,0.f,0.f,0.f,0.f,0.f,0.f,0.f}; \
        { \
            unsigned id[7] = { (q0_).x >> 16, (q0_).y & 0xffffu, (q0_).y >> 16, \
                               (q0_).z & 0xffffu, (q0_).z >> 16, (q0_).w & 0xffffu, (q0_).w >> 16 }; \
            float wk[7]; uint4 g[7]; \
            _Pragma("unroll") \
            for (int k = 0; k < 7; ++k) { \
                bool act = (unsigned)k < c; \
                wk[k] = act ? 1.0f : 0.0f; \
                g[k] = Xeb4[(size_t)(act ? id[k] : 0u) * 16 + hl]; \
            } \
            _Pragma("unroll") \
            for (int k = 0; k < 7; ++k) VACC(g[k], wk[k]); \
        } \
        if (c > 7) { \
            unsigned id[8] = { (q1_).x & 0xffffu, (q1_).x >> 16, (q1_).y & 0xffffu, (q1_).y >> 16, \
                               (q1_).z & 0xffffu, (q1_).z >> 16, (q1_).w & 0xffffu, (q1_).w >> 16 }; \
            float wk[8]; uint4 g[8]; \
            _Pragma("unroll") \
            for (int k = 0; k < 8; ++k) { \
                bool act = (unsigned)(7 + k) < c; \
                wk[k] = act ? 1.0f : 0.0f; \
                g[k] = Xeb4[(size_t)(act ? id[k] : 0u) * 16 + hl]; \
            } \
            _Pragma("unroll") \
            for (int k = 0; k < 8; ++k) VACC(g[k], wk[k]); \
        } \
        if (c > 15) { \
            uint4 q2 = bktq[(size_t)(vv_) * 4 + 2]; \
            uint4 q3 = bktq[(size_t)(vv_) * 4 + 3]; \
            unsigned id[16] = { q2.x & 0xffffu, q2.x >> 16, q2.y & 0xffffu, q2.y >> 16, \
                                q2.z & 0xffffu, q2.z >> 16, q2.w & 0xffffu, q2.w >> 16, \
                                q3.x & 0xffffu, q3.x >> 16, q3.y & 0xffffu, q3.y >> 16, \
                                q3.z & 0xffffu, q3.z >> 16, q3.w & 0xffffu, q3.w >> 16 }; \
            float wk[16]; uint4 g[16]; \
            _Pragma("unroll") \
            for (int k = 0; k < 16; ++k) { \
                bool act = (unsigned)(15 + k) < c; \
                wk[k] = act ? 1.0f : 0.0f; \
                g[k] = Xeb4[(size_t)(act ? id[k] : 0u) * 16 + hl]; \
            } \
            _Pragma("unroll") \
            for (int k = 0; k < 16; ++k) VACC(g[k], wk[k]); \
        } \
        const float s = (1.0f - alpha) * (c ? 1.0f / (float)c : 1.0f); \
        uint4 xiw; \
        xiw.x = pk2(s * a[0] + alpha * (x0a_).x, s * a[1] + alpha * (x0a_).y); \
        xiw.y = pk2(s * a[2] + alpha * (x0a_).z, s * a[3] + alpha * (x0a_).w); \
        xiw.z = pk2(s * a[4] + alpha * (x0b_).x, s * a[5] + alpha * (x0b_).y); \
        xiw.w = pk2(s * a[6] + alpha * (x0b_).z, s * a[7] + alpha * (x0b_).w); \
        *(uint4*)&sXi[row_][hl * 4] = xiw; }

    GATHER_TILE(q0a, q1a, v0, x0a0, x0b0, vrow);
    GATHER_TILE(q0b, q1b, v1, x0a1, x0b1, vrow + 16);
#undef GATHER_TILE
#undef VACC

    __syncthreads();

    // ---- MFMA epilogue: both row-tiles x wave's 2 col-tiles ----
    const size_t obase = (size_t)blockIdx.x * 32 * DIM;
#pragma unroll
    for (int rt = 0; rt < 2; ++rt) {
        const char* ab = (const char*)&sXi[rt * 16 + lr][0] + lg * 16;
        short8 af[4];
#pragma unroll
        for (int kt = 0; kt < 4; ++kt) af[kt] = *(const short8*)(ab + kt * 64);

#pragma unroll
        for (int ctl = 0; ctl < 2; ++ctl) {
            const int ct = wid * 2 + ctl;
            f32x4 acc = {};
#pragma unroll
            for (int kt = 0; kt < 4; ++kt)
                acc = __builtin_amdgcn_mfma_f32_16x16x32_bf16(af[kt], mf[ctl][kt], acc, 0, 0, 0);
#pragma unroll
            for (int rg = 0; rg < 4; ++rg) {
                int row = rt * 16 + lg * 4 + rg;    // D: col=lane&15, row=lg*4+reg
                out[obase + (size_t)row * DIM + ct * 16 + lr] = acc[rg];
            }
        }
    }
}

// ---------------------------------------------------------------------------
extern "C" void kernel_launch(void* const* d_in, const int* in_sizes, int n_in,
                              void* d_out, int out_size, void* d_ws, size_t ws_size,
                              hipStream_t stream) {
    const float* X      = (const float*)d_in[0];
    const int*   vertex = (const int*)  d_in[1];
    const int*   edges  = (const int*)  d_in[2];
    const float* alpha  = (const float*)d_in[3];
    const float* beta   = (const float*)d_in[4];
    const float* X0     = (const float*)d_in[5];
    const float* W      = (const float*)d_in[6];
    float*       out    = (float*)d_out;

    // ws layout (all 16B-aligned)
    unsigned* gpos_e = (unsigned*)d_ws;                        // NB_E (zeroed)
    unsigned* gpos_v = gpos_e + NB_E;                          // NB_V (zeroed)
    unsigned* ebin   = (unsigned*)d_ws + 256;                  // NB_E*CAP_E
    unsigned* vbin   = ebin + (size_t)NB_E * CAP_E;            // NB_V*CAP_V
    int*      bkt_e  = (int*)(vbin + (size_t)NB_V * CAP_V);    // NE*SE
    unsigned short* bkt_v = (unsigned short*)(bkt_e + (size_t)NE * SE); // NV*SV
    unsigned short* Mb = bkt_v + (size_t)NV * SV;              // DIM*DIM
    unsigned* Xeb = (unsigned*)(Mb + DIM * DIM);               // NE*64

    // bf16 X lives in d_out (dead before k_vf2 overwrites out)
    unsigned* Xb = (unsigned*)d_out;                           // NV*64

    hipMemsetAsync(d_ws, 0, (size_t)(NB_E + NB_V) * sizeof(unsigned), stream);

    k_bin<<<BIN_BLOCKS + G_CVT1, 256, 0, stream>>>(
        (const float4*)X, (const float4*)W, beta,
        (const int4*)vertex, (const int4*)edges,
        gpos_e, gpos_v, ebin, vbin, (ushort4*)Xb, (ushort4*)Mb);
    k_bucket<<<NB_E + NB_V + G_CVT2, 256, 0, stream>>>(
        gpos_e, gpos_v, ebin, vbin, bkt_e, bkt_v,
        (const float4*)X, (ushort4*)Xb);
    k_edge<<<EDGE_BLOCKS, 256, 0, stream>>>((const uint4*)Xb,
                                            (const int4*)bkt_e,
                                            (uint4*)Xeb);
    k_vf2<<<VF2_BLOCKS, 256, 0, stream>>>((const uint4*)Xeb, (const uint4*)bkt_v,
                                          (const float4*)X0, alpha,
                                          (const unsigned short*)Mb, out);
}